// Round 2
// baseline (496.333 us; speedup 1.0000x reference)
//
#include <hip/hip_runtime.h>
#include <math.h>

#define NB 4
#define NP 8192
#define KK 16
#define QPB 64
#define NWAVE 4
#define CHUNK (NP / NWAVE)

// reference-matching fp32 distance: d2 = (sq_q + sq_c) - 2*dot, dot = (xx+yy)+zz
__device__ __forceinline__ float ref_d2(float qx, float qy, float qz, float sqq,
                                        float px, float py, float pz, float sqc) {
  float dot = __fadd_rn(__fadd_rn(__fmul_rn(qx, px), __fmul_rn(qy, py)),
                        __fmul_rn(qz, pz));
  float s = __fadd_rn(sqq, sqc);
  return __fmaf_rn(-2.0f, dot, s);   // 2*dot exact => identical to fl(s - 2*dot)
}

__global__ __launch_bounds__(256, 2) void knn_eigen_kernel(
    const float* __restrict__ x, float* __restrict__ out) {
  __shared__ float sq_s[NP];                    // per-candidate |p|^2 (ref rounding)
  __shared__ float s_d[NWAVE][QPB][KK + 1];     // +1 pad: conflict-free merge reads
  __shared__ int   s_j[NWAVE][QPB][KK + 1];

  const int tid   = threadIdx.x;
  const int lane  = tid & 63;
  const int w     = __builtin_amdgcn_readfirstlane(tid >> 6);
  const int batch = blockIdx.x >> 7;            // 128 blocks per batch
  const int qbase = (blockIdx.x & 127) * QPB;

  const float* __restrict__ Xb = x + (size_t)batch * NP * 3;

  // ---- fill sq table for the whole batch (ref rounding: (xx+yy)+zz)
  for (int i = tid; i < NP; i += 256) {
    float px = Xb[3 * i + 0], py = Xb[3 * i + 1], pz = Xb[3 * i + 2];
    sq_s[i] = __fadd_rn(__fadd_rn(__fmul_rn(px, px), __fmul_rn(py, py)),
                        __fmul_rn(pz, pz));
  }
  __syncthreads();

  // query point (per-lane)
  const int qi = qbase + lane;
  const float qx = Xb[qi * 3 + 0];
  const float qy = Xb[qi * 3 + 1];
  const float qz = Xb[qi * 3 + 2];
  const float sqq = sq_s[qi];

  // ---- phase 1: exact top-16 DISTANCES over this wave's 2048-candidate chunk
  float bd[KK];
#pragma unroll
  for (int t = 0; t < KK; ++t) bd[t] = 3.4e38f;

  const int j0 = w * CHUNK;
  for (int jj = 0; jj < CHUNK; jj += 8) {
    float c[24];
    const float* xp = Xb + (size_t)(j0 + jj) * 3;   // wave-uniform -> s_load
#pragma unroll
    for (int u = 0; u < 24; ++u) c[u] = xp[u];
    float sc[8];
#pragma unroll
    for (int u = 0; u < 8; ++u) sc[u] = sq_s[j0 + jj + u];  // uniform -> broadcast
#pragma unroll
    for (int u = 0; u < 4; ++u) {
      float d0 = ref_d2(qx, qy, qz, sqq, c[6*u+0], c[6*u+1], c[6*u+2], sc[2*u+0]);
      float d1 = ref_d2(qx, qy, qz, sqq, c[6*u+3], c[6*u+4], c[6*u+5], sc[2*u+1]);
      float m = fminf(d0, d1);
      float M = fmaxf(d0, d1);
      // branchless sorted insert of the pair (merge-network identity)
#pragma unroll
      for (int t = KK - 1; t >= 2; --t)
        bd[t] = fmaxf(bd[t-2], fmaxf(fminf(bd[t-1], M), fminf(bd[t], m)));
      bd[1] = fmaxf(fminf(bd[0], M), fminf(bd[1], m));
      bd[0] = fminf(bd[0], m);
    }
  }

  const float T = bd[KK - 1];   // exact 16th-smallest (ref-rounded) in chunk

  // ---- phase 2: recover indices (ascending j => matches stable top_k ties)
  int cnt = 0;
  for (int jj = 0; jj < CHUNK; jj += 4) {
    float c[12];
    const float* xp = Xb + (size_t)(j0 + jj) * 3;
#pragma unroll
    for (int u = 0; u < 12; ++u) c[u] = xp[u];
    float sc[4];
#pragma unroll
    for (int u = 0; u < 4; ++u) sc[u] = sq_s[j0 + jj + u];
#pragma unroll
    for (int u = 0; u < 4; ++u) {
      float d = ref_d2(qx, qy, qz, sqq, c[3*u+0], c[3*u+1], c[3*u+2], sc[u]);
      if (d <= T && cnt < KK) {
        s_d[w][lane][cnt] = d;
        s_j[w][lane][cnt] = j0 + jj + u;
        cnt++;
      }
    }
  }

  __syncthreads();

  // ---- merge 4 chunk-lists + covariance + eigen: wave w handles 16 queries
  if (lane < KK) {
    const int ql = w * KK + lane;
    float md[KK]; int mj[KK];
#pragma unroll
    for (int t = 0; t < KK; ++t) { md[t] = 3.4e38f; mj[t] = 0; }

    for (int cch = 0; cch < NWAVE; ++cch) {
#pragma unroll
      for (int s = 0; s < KK; ++s) {
        float d = s_d[cch][ql][s];
        int   j = s_j[cch][ql][s];
        if (d < md[KK - 1]) {
          bool c0 = d < md[0];
#pragma unroll
          for (int t = KK - 1; t >= 1; --t) {
            bool cl = d < md[t];
            bool cp = d < md[t-1];
            float nv = fmaxf(md[t-1], fminf(md[t], d));
            mj[t] = cl ? (cp ? mj[t-1] : j) : mj[t];
            md[t] = nv;
          }
          mj[0] = c0 ? j : mj[0];
          md[0] = fminf(md[0], d);
        }
      }
    }

    // mean of the 16 neighbors (sequential fp32, then exact /16)
    float sx = 0.f, sy = 0.f, sz = 0.f;
#pragma unroll
    for (int s = 0; s < KK; ++s) {
      const float* pp = Xb + (size_t)mj[s] * 3;
      sx = __fadd_rn(sx, pp[0]);
      sy = __fadd_rn(sy, pp[1]);
      sz = __fadd_rn(sz, pp[2]);
    }
    const float k1 = 1.0f / KK;   // exact power of two
    const float mx = sx * k1, my = sy * k1, mz = sz * k1;

    // covariance: plain fp32 mul-then-add (no fma), sequential k order
    float cxx = 0.f, cxy = 0.f, cxz = 0.f, cyy = 0.f, cyz = 0.f, czz = 0.f;
#pragma unroll
    for (int s = 0; s < KK; ++s) {
      const float* pp = Xb + (size_t)mj[s] * 3;
      float dx = __fsub_rn(pp[0], mx);
      float dy = __fsub_rn(pp[1], my);
      float dz = __fsub_rn(pp[2], mz);
      cxx = __fadd_rn(cxx, __fmul_rn(dx, dx));
      cxy = __fadd_rn(cxy, __fmul_rn(dx, dy));
      cxz = __fadd_rn(cxz, __fmul_rn(dx, dz));
      cyy = __fadd_rn(cyy, __fmul_rn(dy, dy));
      cyz = __fadd_rn(cyz, __fmul_rn(dy, dz));
      czz = __fadd_rn(czz, __fmul_rn(dz, dz));
    }

    // closed-form symmetric 3x3 eigenvalues in double (exact wrt fp32 cov)
    double a   = (double)__fmul_rn(cxx, k1), b = (double)__fmul_rn(cyy, k1);
    double c2  = (double)__fmul_rn(czz, k1);
    double dxy = (double)__fmul_rn(cxy, k1), exz = (double)__fmul_rn(cxz, k1);
    double fyz = (double)__fmul_rn(cyz, k1);
    double qm = (a + b + c2) / 3.0;
    double p1 = dxy * dxy + exz * exz + fyz * fyz;
    double aa = a - qm, bb = b - qm, cc = c2 - qm;
    double p2 = aa * aa + bb * bb + cc * cc + 2.0 * p1;
    double ratio;
    if (p2 <= 0.0) {
      ratio = 1.0;
    } else {
      double p  = sqrt(p2 / 6.0);
      double ip = 1.0 / p;
      double b00 = aa * ip, b11 = bb * ip, b22 = cc * ip;
      double b01 = dxy * ip, b02 = exz * ip, b12 = fyz * ip;
      double detB = b00 * (b11 * b22 - b12 * b12)
                  - b01 * (b01 * b22 - b12 * b02)
                  + b02 * (b01 * b12 - b11 * b02);
      double r = 0.5 * detB;
      r = fmin(1.0, fmax(-1.0, r));
      double phi = acos(r) / 3.0;
      double e0 = qm + 2.0 * p * cos(phi);                      // largest
      double e2 = qm + 2.0 * p * cos(phi + 2.0943951023931954); // smallest
      double e1 = 3.0 * qm - e0 - e2;                           // middle
      ratio = e0 / e1;
    }
    out[(size_t)batch * NP + qbase + ql] = (float)ratio;
  }
}

extern "C" void kernel_launch(void* const* d_in, const int* in_sizes, int n_in,
                              void* d_out, int out_size, void* d_ws, size_t ws_size,
                              hipStream_t stream) {
  const float* x = (const float*)d_in[0];
  float* out = (float*)d_out;
  // k (d_in[1]) is fixed at 16 for this problem
  knn_eigen_kernel<<<dim3((NB * NP) / QPB), dim3(NWAVE * 64), 0, stream>>>(x, out);
}

// Round 3
// 474.824 us; speedup vs baseline: 1.0453x; 1.0453x over previous
//
#include <hip/hip_runtime.h>
#include <math.h>

#define NB 4
#define NP 8192
#define KK 16
#define QPB 64
#define NWAVE 8
#define CHUNK (NP / NWAVE)   // 1024
#define NPTS (NB * NP)

// reference-rounded |p|^2 : (xx+yy)+zz
__device__ __forceinline__ float ref_sq(float x, float y, float z) {
  return __fadd_rn(__fadd_rn(__fmul_rn(x, x), __fmul_rn(y, y)), __fmul_rn(z, z));
}

// reference-rounded d2 = (sqq + sqc) - 2*dot, dot = (xx+yy)+zz
__device__ __forceinline__ float ref_d2q(float qx, float qy, float qz, float sqq,
                                         float4 c) {
  float dot = __fadd_rn(__fadd_rn(__fmul_rn(qx, c.x), __fmul_rn(qy, c.y)),
                        __fmul_rn(qz, c.z));
  float s = __fadd_rn(sqq, c.w);
  return __fmaf_rn(-2.0f, dot, s);   // 2*dot exact => identical to fl(s - 2*dot)
}

__global__ void prep_kernel(const float* __restrict__ x,
                            float4* __restrict__ cand) {
  int i = blockIdx.x * 256 + threadIdx.x;
  if (i < NPTS) {
    float px = x[3 * i + 0], py = x[3 * i + 1], pz = x[3 * i + 2];
    cand[i] = make_float4(px, py, pz, ref_sq(px, py, pz));
  }
}

__global__ __launch_bounds__(512, 4) void knn_eigen_kernel(
    const float4* __restrict__ cand, float* __restrict__ out) {
  // per-chunk top-16 neighbor indices (batch-relative, <8192 fits ushort)
  // row padded to 18 (9 dwords) -> conflict-free strided reads in merge
  __shared__ unsigned short s_j[NWAVE][QPB][18];

  const int tid   = threadIdx.x;
  const int lane  = tid & 63;
  const int w     = __builtin_amdgcn_readfirstlane(tid >> 6);
  const int batch = blockIdx.x >> 7;            // 128 blocks per batch
  const int qbase = (blockIdx.x & 127) * QPB;

  const float4* __restrict__ Cb = cand + (size_t)batch * NP;

  // query point (per-lane)
  const float4 q = Cb[qbase + lane];
  const float qx = q.x, qy = q.y, qz = q.z, sqq = q.w;

  // ---- phase 1: exact top-16 DISTANCES over this wave's 1024-candidate chunk
  float bd[KK];
#pragma unroll
  for (int t = 0; t < KK; ++t) bd[t] = 3.4e38f;

  const int j0 = w * CHUNK;
  for (int jj = 0; jj < CHUNK; jj += 8) {
    const float4* xp = Cb + (j0 + jj);          // wave-uniform address
    float4 c[8];
#pragma unroll
    for (int u = 0; u < 8; ++u) c[u] = xp[u];
#pragma unroll
    for (int u = 0; u < 4; ++u) {
      float d0 = ref_d2q(qx, qy, qz, sqq, c[2 * u + 0]);
      float d1 = ref_d2q(qx, qy, qz, sqq, c[2 * u + 1]);
      float m = fminf(d0, d1);
      float M = fmaxf(d0, d1);
      // branchless sorted insert of the pair (merge-network identity)
#pragma unroll
      for (int t = KK - 1; t >= 2; --t)
        bd[t] = fmaxf(bd[t - 2], fmaxf(fminf(bd[t - 1], M), fminf(bd[t], m)));
      bd[1] = fmaxf(fminf(bd[0], M), fminf(bd[1], m));
      bd[0] = fminf(bd[0], m);
    }
  }

  const float T = bd[KK - 1];   // exact 16th-smallest (ref-rounded) in chunk

  // ---- phase 2: recover indices (ascending j => matches stable top_k ties)
  int cnt = 0;
  for (int jj = 0; jj < CHUNK; jj += 4) {
    const float4* xp = Cb + (j0 + jj);
    float4 c[4];
#pragma unroll
    for (int u = 0; u < 4; ++u) c[u] = xp[u];
#pragma unroll
    for (int u = 0; u < 4; ++u) {
      float d = ref_d2q(qx, qy, qz, sqq, c[u]);
      if (d <= T && cnt < KK) {
        s_j[w][lane][cnt] = (unsigned short)(j0 + jj + u);
        cnt++;
      }
    }
  }

  __syncthreads();

  // ---- merge 8 chunk-lists + covariance + eigen: wave 0, one query per lane
  if (tid < QPB) {
    const float4 qq = Cb[qbase + tid];
    const float q2x = qq.x, q2y = qq.y, q2z = qq.z, sq2 = qq.w;

    float md[KK]; int mj[KK];
#pragma unroll
    for (int t = 0; t < KK; ++t) { md[t] = 3.4e38f; mj[t] = 0; }

    for (int cch = 0; cch < NWAVE; ++cch) {
      const unsigned int* rowp = (const unsigned int*)&s_j[cch][tid][0];
#pragma unroll
      for (int sp = 0; sp < KK / 2; ++sp) {
        unsigned int pk = rowp[sp];
#pragma unroll
        for (int half = 0; half < 2; ++half) {
          int j = (half == 0) ? (int)(pk & 0xFFFFu) : (int)(pk >> 16);
          float d = ref_d2q(q2x, q2y, q2z, sq2, Cb[j]);
          if (d < md[KK - 1]) {
            bool c0 = d < md[0];
#pragma unroll
            for (int t = KK - 1; t >= 1; --t) {
              bool cl = d < md[t];
              bool cp = d < md[t - 1];
              float nv = fmaxf(md[t - 1], fminf(md[t], d));
              mj[t] = cl ? (cp ? mj[t - 1] : j) : mj[t];
              md[t] = nv;
            }
            mj[0] = c0 ? j : mj[0];
            md[0] = fminf(md[0], d);
          }
        }
      }
    }

    // mean of the 16 neighbors (sequential fp32, then exact /16)
    float sx = 0.f, sy = 0.f, sz = 0.f;
#pragma unroll
    for (int s = 0; s < KK; ++s) {
      float4 pp = Cb[mj[s]];
      sx = __fadd_rn(sx, pp.x);
      sy = __fadd_rn(sy, pp.y);
      sz = __fadd_rn(sz, pp.z);
    }
    const float k1 = 1.0f / KK;   // exact power of two
    const float mx = sx * k1, my = sy * k1, mz = sz * k1;

    // covariance: plain fp32 mul-then-add (no fma), sequential k order
    float cxx = 0.f, cxy = 0.f, cxz = 0.f, cyy = 0.f, cyz = 0.f, czz = 0.f;
#pragma unroll
    for (int s = 0; s < KK; ++s) {
      float4 pp = Cb[mj[s]];
      float dx = __fsub_rn(pp.x, mx);
      float dy = __fsub_rn(pp.y, my);
      float dz = __fsub_rn(pp.z, mz);
      cxx = __fadd_rn(cxx, __fmul_rn(dx, dx));
      cxy = __fadd_rn(cxy, __fmul_rn(dx, dy));
      cxz = __fadd_rn(cxz, __fmul_rn(dx, dz));
      cyy = __fadd_rn(cyy, __fmul_rn(dy, dy));
      cyz = __fadd_rn(cyz, __fmul_rn(dy, dz));
      czz = __fadd_rn(czz, __fmul_rn(dz, dz));
    }

    // closed-form symmetric 3x3 eigenvalues in double (exact wrt fp32 cov)
    double a   = (double)__fmul_rn(cxx, k1), b = (double)__fmul_rn(cyy, k1);
    double c2  = (double)__fmul_rn(czz, k1);
    double dxy = (double)__fmul_rn(cxy, k1), exz = (double)__fmul_rn(cxz, k1);
    double fyz = (double)__fmul_rn(cyz, k1);
    double qm = (a + b + c2) / 3.0;
    double p1 = dxy * dxy + exz * exz + fyz * fyz;
    double aa = a - qm, bb = b - qm, cc = c2 - qm;
    double p2 = aa * aa + bb * bb + cc * cc + 2.0 * p1;
    double ratio;
    if (p2 <= 0.0) {
      ratio = 1.0;
    } else {
      double p  = sqrt(p2 / 6.0);
      double ip = 1.0 / p;
      double b00 = aa * ip, b11 = bb * ip, b22 = cc * ip;
      double b01 = dxy * ip, b02 = exz * ip, b12 = fyz * ip;
      double detB = b00 * (b11 * b22 - b12 * b12)
                  - b01 * (b01 * b22 - b12 * b02)
                  + b02 * (b01 * b12 - b11 * b02);
      double r = 0.5 * detB;
      r = fmin(1.0, fmax(-1.0, r));
      double phi = acos(r) / 3.0;
      double e0 = qm + 2.0 * p * cos(phi);                      // largest
      double e2 = qm + 2.0 * p * cos(phi + 2.0943951023931954); // smallest
      double e1 = 3.0 * qm - e0 - e2;                           // middle
      ratio = e0 / e1;
    }
    out[(size_t)batch * NP + qbase + tid] = (float)ratio;
  }
}

extern "C" void kernel_launch(void* const* d_in, const int* in_sizes, int n_in,
                              void* d_out, int out_size, void* d_ws, size_t ws_size,
                              hipStream_t stream) {
  const float* x = (const float*)d_in[0];
  float* out = (float*)d_out;
  float4* cand = (float4*)d_ws;   // NPTS * 16 B = 512 KB scratch
  prep_kernel<<<dim3(NPTS / 256), dim3(256), 0, stream>>>(x, cand);
  knn_eigen_kernel<<<dim3((NB * NP) / QPB), dim3(NWAVE * 64), 0, stream>>>(cand, out);
}

// Round 4
// 379.381 us; speedup vs baseline: 1.3083x; 1.2516x over previous
//
#include <hip/hip_runtime.h>
#include <math.h>

#define NB 4
#define NP 8192
#define KK 16
#define QPB 64
#define NWAVE 8
#define CHUNK (NP / NWAVE)   // 1024
#define NPTS (NB * NP)

// comparator macros (exact: min/max introduce no rounding)
#define CSWAP_DESC(a, b) { float _lo = fminf(a, b); float _hi = fmaxf(a, b); a = _hi; b = _lo; }
#define CSWAP_ASC(a, b)  { float _lo = fminf(a, b); float _hi = fmaxf(a, b); a = _lo; b = _hi; }

// reference-rounded |p|^2 : (xx+yy)+zz
__device__ __forceinline__ float ref_sq(float x, float y, float z) {
  return __fadd_rn(__fadd_rn(__fmul_rn(x, x), __fmul_rn(y, y)), __fmul_rn(z, z));
}

// reference-rounded d2 = (sqq + sqc) - 2*dot, dot = (xx+yy)+zz
__device__ __forceinline__ float ref_d2q(float qx, float qy, float qz, float sqq,
                                         float4 c) {
  float dot = __fadd_rn(__fadd_rn(__fmul_rn(qx, c.x), __fmul_rn(qy, c.y)),
                        __fmul_rn(qz, c.z));
  float s = __fadd_rn(sqq, c.w);
  return __fmaf_rn(-2.0f, dot, s);   // 2*dot exact => identical to fl(s - 2*dot)
}

__global__ void prep_kernel(const float* __restrict__ x,
                            float4* __restrict__ cand) {
  int i = blockIdx.x * 256 + threadIdx.x;
  if (i < NPTS) {
    float px = x[3 * i + 0], py = x[3 * i + 1], pz = x[3 * i + 2];
    cand[i] = make_float4(px, py, pz, ref_sq(px, py, pz));
  }
}

__global__ __launch_bounds__(512, 4) void knn_eigen_kernel(
    const float4* __restrict__ cand, float* __restrict__ out) {
  // per-chunk top-16 neighbor indices (batch-relative, <8192 fits ushort)
  // row padded to 18 (9 dwords) -> conflict-free strided reads in merge
  __shared__ unsigned short s_j[NWAVE][QPB][18];

  const int tid   = threadIdx.x;
  const int lane  = tid & 63;
  const int w     = __builtin_amdgcn_readfirstlane(tid >> 6);
  const int batch = blockIdx.x >> 7;            // 128 blocks per batch
  const int qbase = (blockIdx.x & 127) * QPB;

  const float4* __restrict__ Cb = cand + (size_t)batch * NP;

  // query point (per-lane)
  const float4 q = Cb[qbase + lane];
  const float qx = q.x, qy = q.y, qz = q.z, sqq = q.w;

  // ---- phase 1: exact top-16 DISTANCES over this wave's 1024-candidate chunk
  // bd[0..15] sorted ascending invariant: the 16 smallest seen so far
  float bd[KK];
#pragma unroll
  for (int t = 0; t < KK; ++t) bd[t] = 3.4e38f;

  const int j0 = w * CHUNK;
  for (int jj = 0; jj < CHUNK; jj += 8) {
    const float4* xp = Cb + (j0 + jj);          // wave-uniform address
    float4 c[8];
#pragma unroll
    for (int u = 0; u < 8; ++u) c[u] = xp[u];

    float d[8];
#pragma unroll
    for (int u = 0; u < 8; ++u) d[u] = ref_d2q(qx, qy, qz, sqq, c[u]);

    // Batcher odd-even mergesort-8, DESCENDING (19 comparators)
    CSWAP_DESC(d[0], d[1]) CSWAP_DESC(d[2], d[3]) CSWAP_DESC(d[4], d[5]) CSWAP_DESC(d[6], d[7])
    CSWAP_DESC(d[0], d[2]) CSWAP_DESC(d[1], d[3]) CSWAP_DESC(d[4], d[6]) CSWAP_DESC(d[5], d[7])
    CSWAP_DESC(d[1], d[2]) CSWAP_DESC(d[5], d[6])
    CSWAP_DESC(d[0], d[4]) CSWAP_DESC(d[1], d[5]) CSWAP_DESC(d[2], d[6]) CSWAP_DESC(d[3], d[7])
    CSWAP_DESC(d[2], d[4]) CSWAP_DESC(d[3], d[5])
    CSWAP_DESC(d[1], d[2]) CSWAP_DESC(d[3], d[4]) CSWAP_DESC(d[5], d[6])

    // [bd_asc(16), +inf x8, d_desc(8)] is bitonic; halver keeps 16 smallest:
    // lower half = [bd[0..7], min(bd[8+i], d[i])] (bitonic)
#pragma unroll
    for (int i = 0; i < 8; ++i) bd[8 + i] = fminf(bd[8 + i], d[i]);

    // bitonic merge-16 ascending cleanup (32 comparators)
#pragma unroll
    for (int i = 0; i < 8; ++i)  CSWAP_ASC(bd[i], bd[i + 8])
#pragma unroll
    for (int i = 0; i < 4; ++i)  CSWAP_ASC(bd[i], bd[i + 4])
#pragma unroll
    for (int i = 8; i < 12; ++i) CSWAP_ASC(bd[i], bd[i + 4])
#pragma unroll
    for (int g = 0; g < 4; ++g) {
      CSWAP_ASC(bd[4 * g + 0], bd[4 * g + 2]) CSWAP_ASC(bd[4 * g + 1], bd[4 * g + 3])
      CSWAP_ASC(bd[4 * g + 0], bd[4 * g + 1]) CSWAP_ASC(bd[4 * g + 2], bd[4 * g + 3])
    }
  }

  const float T = bd[KK - 1];   // exact 16th-smallest (ref-rounded) in chunk

  // ---- phase 2: recover indices (ascending j => matches stable top_k ties)
  int cnt = 0;
  for (int jj = 0; jj < CHUNK; jj += 8) {
    const float4* xp = Cb + (j0 + jj);
    float4 c[8];
#pragma unroll
    for (int u = 0; u < 8; ++u) c[u] = xp[u];
#pragma unroll
    for (int u = 0; u < 8; ++u) {
      float d = ref_d2q(qx, qy, qz, sqq, c[u]);
      if (d <= T && cnt < KK) {
        s_j[w][lane][cnt] = (unsigned short)(j0 + jj + u);
        cnt++;
      }
    }
  }

  __syncthreads();

  // ---- merge 8 chunk-lists + covariance + eigen: wave 0, one query per lane
  if (tid < QPB) {
    const float4 qq = Cb[qbase + tid];
    const float q2x = qq.x, q2y = qq.y, q2z = qq.z, sq2 = qq.w;

    float md[KK]; int mj[KK];
#pragma unroll
    for (int t = 0; t < KK; ++t) { md[t] = 3.4e38f; mj[t] = 0; }

    for (int cch = 0; cch < NWAVE; ++cch) {
      const unsigned int* rowp = (const unsigned int*)&s_j[cch][tid][0];
#pragma unroll
      for (int sp = 0; sp < KK / 2; ++sp) {
        unsigned int pk = rowp[sp];
#pragma unroll
        for (int half = 0; half < 2; ++half) {
          int j = (half == 0) ? (int)(pk & 0xFFFFu) : (int)(pk >> 16);
          float d = ref_d2q(q2x, q2y, q2z, sq2, Cb[j]);
          if (d < md[KK - 1]) {
            bool c0 = d < md[0];
#pragma unroll
            for (int t = KK - 1; t >= 1; --t) {
              bool cl = d < md[t];
              bool cp = d < md[t - 1];
              float nv = fmaxf(md[t - 1], fminf(md[t], d));
              mj[t] = cl ? (cp ? mj[t - 1] : j) : mj[t];
              md[t] = nv;
            }
            mj[0] = c0 ? j : mj[0];
            md[0] = fminf(md[0], d);
          }
        }
      }
    }

    // mean of the 16 neighbors (sequential fp32, then exact /16)
    float sx = 0.f, sy = 0.f, sz = 0.f;
#pragma unroll
    for (int s = 0; s < KK; ++s) {
      float4 pp = Cb[mj[s]];
      sx = __fadd_rn(sx, pp.x);
      sy = __fadd_rn(sy, pp.y);
      sz = __fadd_rn(sz, pp.z);
    }
    const float k1 = 1.0f / KK;   // exact power of two
    const float mx = sx * k1, my = sy * k1, mz = sz * k1;

    // covariance: plain fp32 mul-then-add (no fma), sequential k order
    float cxx = 0.f, cxy = 0.f, cxz = 0.f, cyy = 0.f, cyz = 0.f, czz = 0.f;
#pragma unroll
    for (int s = 0; s < KK; ++s) {
      float4 pp = Cb[mj[s]];
      float dx = __fsub_rn(pp.x, mx);
      float dy = __fsub_rn(pp.y, my);
      float dz = __fsub_rn(pp.z, mz);
      cxx = __fadd_rn(cxx, __fmul_rn(dx, dx));
      cxy = __fadd_rn(cxy, __fmul_rn(dx, dy));
      cxz = __fadd_rn(cxz, __fmul_rn(dx, dz));
      cyy = __fadd_rn(cyy, __fmul_rn(dy, dy));
      cyz = __fadd_rn(cyz, __fmul_rn(dy, dz));
      czz = __fadd_rn(czz, __fmul_rn(dz, dz));
    }

    // closed-form symmetric 3x3 eigenvalues in double (exact wrt fp32 cov)
    double a   = (double)__fmul_rn(cxx, k1), b = (double)__fmul_rn(cyy, k1);
    double c2  = (double)__fmul_rn(czz, k1);
    double dxy = (double)__fmul_rn(cxy, k1), exz = (double)__fmul_rn(cxz, k1);
    double fyz = (double)__fmul_rn(cyz, k1);
    double qm = (a + b + c2) / 3.0;
    double p1 = dxy * dxy + exz * exz + fyz * fyz;
    double aa = a - qm, bb = b - qm, cc = c2 - qm;
    double p2 = aa * aa + bb * bb + cc * cc + 2.0 * p1;
    double ratio;
    if (p2 <= 0.0) {
      ratio = 1.0;
    } else {
      double p  = sqrt(p2 / 6.0);
      double ip = 1.0 / p;
      double b00 = aa * ip, b11 = bb * ip, b22 = cc * ip;
      double b01 = dxy * ip, b02 = exz * ip, b12 = fyz * ip;
      double detB = b00 * (b11 * b22 - b12 * b12)
                  - b01 * (b01 * b22 - b12 * b02)
                  + b02 * (b01 * b12 - b11 * b02);
      double r = 0.5 * detB;
      r = fmin(1.0, fmax(-1.0, r));
      double phi = acos(r) / 3.0;
      double e0 = qm + 2.0 * p * cos(phi);                      // largest
      double e2 = qm + 2.0 * p * cos(phi + 2.0943951023931954); // smallest
      double e1 = 3.0 * qm - e0 - e2;                           // middle
      ratio = e0 / e1;
    }
    out[(size_t)batch * NP + qbase + tid] = (float)ratio;
  }
}

extern "C" void kernel_launch(void* const* d_in, const int* in_sizes, int n_in,
                              void* d_out, int out_size, void* d_ws, size_t ws_size,
                              hipStream_t stream) {
  const float* x = (const float*)d_in[0];
  float* out = (float*)d_out;
  float4* cand = (float4*)d_ws;   // NPTS * 16 B = 512 KB scratch
  prep_kernel<<<dim3(NPTS / 256), dim3(256), 0, stream>>>(x, cand);
  knn_eigen_kernel<<<dim3((NB * NP) / QPB), dim3(NWAVE * 64), 0, stream>>>(cand, out);
}